// Round 6
// baseline (59.906 us; speedup 1.0000x reference)
//
#include <hip/hip_runtime.h>

// ---------------------------------------------------------------------------
// Joint network: y = relu(f@W1t^T + g@W1p^T + (b1t+b1p)) @ W2^T + b2
// N=32768, K1=1344 (1024 f + 320 g), J=512, KOUT=29. fp32 in/out, bf16 MFMA.
// R6: R5 geometry (BM=64, 8 waves, 64x64 wave tile, 2 blocks/CU) +
//     B double-buffered in LDS via global_load_lds issued ONE STEP AHEAD,
//     counted VMCNT(1) (A depth-2 prefetch never drained). W2 from L2.
// ---------------------------------------------------------------------------

typedef float  f32x4  __attribute__((ext_vector_type(4)));
typedef short  s16x8  __attribute__((ext_vector_type(8)));   // 8 bf16
typedef short  s16x4  __attribute__((ext_vector_type(4)));   // 4 bf16

#define N_ROWS   32768
#define NKS      42            // K1 / 32
#define KOUT     29

#define WC_ELEMS   (NKS * 4 * 512 * 8)   // 688128 bf16: [ks][kc][j][8]
#define W2C_ELEMS  (64 * 32 * 8)         // 16384 bf16:  [jc][kout32][8]

#define VMCNT(n)   asm volatile("s_waitcnt vmcnt(" #n ")" ::: "memory")
#define LGKM0()    asm volatile("s_waitcnt lgkmcnt(0)" ::: "memory")
#define SBAR()     __builtin_amdgcn_s_barrier()
#define SCHEDB()   __builtin_amdgcn_sched_barrier(0)
#define PRIO(n)    __builtin_amdgcn_s_setprio(n)

typedef const __attribute__((address_space(1))) unsigned int* gp_t;
typedef __attribute__((address_space(3))) unsigned int* lp_t;

static __device__ __forceinline__ void gls16(const void* g, void* l) {
  __builtin_amdgcn_global_load_lds((gp_t)g, (lp_t)l, 16, 0, 0);
}

static __device__ __forceinline__ unsigned short f2bf(float x) {
  union { float f; unsigned u; } v; v.f = x;
  unsigned r = v.u + 0x7fffu + ((v.u >> 16) & 1u);   // RNE
  return (unsigned short)(r >> 16);
}

// ---------------------------------------------------------------------------
__global__ __launch_bounds__(512) void prep_kernel(
    const float* __restrict__ W1t, const float* __restrict__ b1t,
    const float* __restrict__ W1p, const float* __restrict__ b1p,
    const float* __restrict__ W2,  const float* __restrict__ b2,
    unsigned short* __restrict__ Wc, unsigned short* __restrict__ W2c,
    float* __restrict__ bc, float* __restrict__ b2c) {
  int idx = blockIdx.x * 512 + threadIdx.x;
  if (idx < WC_ELEMS) {
    int e  = idx & 7;
    int j  = (idx >> 3) & 511;
    int kc = (idx >> 12) & 3;
    int ks = idx >> 14;
    int c  = ks * 32 + kc * 8 + e;
    float v = (c < 1024) ? W1t[j * 1024 + c] : W1p[j * 320 + (c - 1024)];
    Wc[idx] = f2bf(v);
  }
  if (idx < W2C_ELEMS) {
    int e  = idx & 7;
    int ko = (idx >> 3) & 31;
    int jc = idx >> 8;
    int j  = jc * 8 + e;
    float v = (ko < KOUT) ? W2[ko * 512 + j] : 0.0f;
    W2c[idx] = f2bf(v);
  }
  if (idx < 512) bc[idx]  = b1t[idx] + b1p[idx];
  if (idx < 32)  b2c[idx] = (idx < KOUT) ? b2[idx] : 0.0f;
}

// ---------------------------------------------------------------------------
// 512 blocks x 512 threads (8 waves). Block tile 64 x 512.
// Wave w: 64 rows x cols [w*64, (w+1)*64) : 4m x 4n of 16x16 tiles.
// LDS: A dbuf [2][4kc][64row][8]  @0     (8 KB, XOR-swizzled)
//      B dbuf [2][4kc][512j][8]   @8192  (64 KB, gls-linear, 1-step-ahead)
//      phase2 h-chunk [16pl][64r][8] @0  (16 KB, aliases A+B0 after K loop)
// Total 72 KB -> 2 blocks/CU (16 waves/CU) with total regs <= 128/wave.
// ---------------------------------------------------------------------------
__global__ __launch_bounds__(512, 4) void joint_kernel(
    const float* __restrict__ f, const float* __restrict__ g,
    const unsigned short* __restrict__ Wc, const unsigned short* __restrict__ W2c,
    const float* __restrict__ bc, const float* __restrict__ b2c,
    float* __restrict__ out) {
  __shared__ __align__(16) char smem[73728];

  const int tid = threadIdx.x;
  const int l   = tid & 63;
  const int w   = tid >> 6;          // wave 0..7 (col slice w*64)
  const int m0  = blockIdx.x * 64;

  // A staging mapping: row = tid>>3 (64), kq = tid&7 (8 x 4 fp32 = 32 k)
  const int srow = tid >> 3;
  const int kq   = tid & 7;
  const char* fA = (const char*)(f + (size_t)(m0 + srow) * 1024 + kq * 4);
  const char* gA = (const char*)(g + (size_t)(m0 + srow) * 320  + kq * 4);
  const int kcpl = kq >> 1;
  const unsigned a_wr = (unsigned)(kcpl * 1024 +
      ((srow * 16 + (kq & 1) * 8) ^ (kcpl << 5)));

  // fragment read offsets
  const int kcg = l >> 4;            // 0..3
  const int lc  = l & 15;
  const unsigned a_rd = (unsigned)(kcg * 1024 + ((lc * 16) ^ (kcg << 5)));
  const unsigned b_rd = (unsigned)(8192 + kcg * 8192 + (w * 64 + lc) * 16);

  f32x4 acc[4][4];
#pragma unroll
  for (int m = 0; m < 4; m++)
#pragma unroll
    for (int n = 0; n < 4; n++) acc[m][n] = (f32x4)(0.0f);

  f32x4 rawE, rawO;   // A prefetch ping-pong (depth 2)

#define STAGE_A(BUF, SRCREG) {                                              \
    s16x4 hv;                                                               \
    hv[0] = (short)f2bf(SRCREG[0]); hv[1] = (short)f2bf(SRCREG[1]);         \
    hv[2] = (short)f2bf(SRCREG[2]); hv[3] = (short)f2bf(SRCREG[3]);         \
    *(s16x4*)(smem + (BUF) * 4096 + a_wr) = hv;                             \
  }

#define GLS_B(T, BUF) {                                                     \
    const char* bs_ = (const char*)Wc + (size_t)(T) * 32768 + tid * 16;     \
    char* bd_ = smem + 8192 + (BUF) * 32768 + tid * 16;                     \
    gls16(bs_,          bd_);                                               \
    gls16(bs_ +  8192,  bd_ +  8192);                                       \
    gls16(bs_ + 16384,  bd_ + 16384);                                       \
    gls16(bs_ + 24576,  bd_ + 24576);                                       \
  }

  // Step T: gls B(T+1) into buf (T+1)&1; read A/B frags from bufs T&1;
  // issue A(T+2) (newest in queue, pinned by SCHEDB); 16 MFMA; stage A(T+1);
  // VMCNT(VM) leaves only A(T+2) in flight; one barrier.
#define K_STEP(T, CONS, ISSU, DO_B, DO_A, ASRC, DO_WR, VMACRO) {            \
    if (DO_B) { GLS_B((T) + 1, ((T) + 1) & 1); }                            \
    s16x8 bq[4];                                                            \
    _Pragma("unroll")                                                       \
    for (int n = 0; n < 4; n++)                                             \
      bq[n] = *(const s16x8*)(smem + ((T) & 1) * 32768 + b_rd + n * 256);   \
    s16x8 af[4];                                                            \
    _Pragma("unroll")                                                       \
    for (int m = 0; m < 4; m++)                                             \
      af[m] = *(const s16x8*)(smem + ((T) & 1) * 4096 + a_rd + m * 256);    \
    if (DO_A) { ISSU = *(const f32x4*)(ASRC); }                             \
    SCHEDB();                                                               \
    PRIO(1);                                                                \
    _Pragma("unroll")                                                       \
    for (int m = 0; m < 4; m++)                                             \
      _Pragma("unroll")                                                     \
      for (int n = 0; n < 4; n++)                                           \
        acc[m][n] = __builtin_amdgcn_mfma_f32_16x16x32_bf16(                \
            af[m], bq[n], acc[m][n], 0, 0, 0);                              \
    PRIO(0);                                                                \
    if (DO_WR) { STAGE_A(((T) + 1) & 1, CONS); }                            \
    VMACRO;                                                                 \
    LGKM0();                                                                \
    SBAR();                                                                 \
  }

  // ---- prologue: gls B(0)->buf0; A(0),A(1)->regs; stage A(0) ----
  GLS_B(0, 0);
  SCHEDB();
  rawE = *(const f32x4*)(fA);          // A(0)
  rawO = *(const f32x4*)(fA + 128);    // A(1)
  STAGE_A(0, rawE);                    // compiler vmcnt(1): drains gls + A(0)
  VMCNT(1);
  LGKM0();
  SBAR();

  // ---- K loop: T=0..41. A(T+2) src: fA for T<=29, gA for 30<=T<=39 ----
  for (int t2 = 0; t2 < 30; t2 += 2) {
    K_STEP(t2,     rawO, rawE, 1, 1, fA + (t2 + 2) * 128, 1, VMCNT(1));
    K_STEP(t2 + 1, rawE, rawO, 1, 1, fA + (t2 + 3) * 128, 1, VMCNT(1));
  }
  K_STEP(30, rawO, rawE, 1, 1, gA,       1, VMCNT(1));
  K_STEP(31, rawE, rawO, 1, 1, gA + 128, 1, VMCNT(1));
  for (int t2 = 32; t2 < 40; t2 += 2) {
    K_STEP(t2,     rawO, rawE, 1, 1, gA + (t2 - 30) * 128, 1, VMCNT(1));
    K_STEP(t2 + 1, rawE, rawO, 1, 1, gA + (t2 - 29) * 128, 1, VMCNT(1));
  }
  K_STEP(40, rawO, rawE, 1, 0, fA, 1, VMCNT(0));   // stages A(41) from rawO
  K_STEP(41, rawE, rawO, 0, 0, fA, 0, VMCNT(0));

  // ---- phase 2: y = relu(h+bias) @ W2^T + b2, h streamed in 4 chunks ----
  // Chunk p: j in [p*128,(p+1)*128), written by waves 2p,2p+1. Then all 8
  // waves MFMA: wave w owns y rows (w&3)*16.., ko (w>>2)*16.. W2 from L2.
  float bias[4];
#pragma unroll
  for (int n = 0; n < 4; n++) bias[n] = bc[w * 64 + n * 16 + lc];

  f32x4 acc2 = (f32x4)(0.0f);
  const int myw = w >> 1;
  const int ko  = (w >> 2) * 16 + lc;
  const unsigned h_rdrow = (unsigned)(((w & 3) * 16 + lc) * 16);

#pragma unroll
  for (int p = 0; p < 4; p++) {
    __syncthreads();                 // h chunk region free
    if (myw == p) {
#pragma unroll
      for (int n = 0; n < 4; n++) {
        const int jrel  = (w & 1) * 64 + n * 16 + lc;
        const int plane = jrel >> 3;
        const unsigned wswz = (unsigned)((plane & 3) << 5);
#pragma unroll
        for (int m = 0; m < 4; m++)
#pragma unroll
          for (int r = 0; r < 4; r++) {
            float v = fmaxf(acc[m][n][r] + bias[n], 0.0f);
            const unsigned rowh = (unsigned)(m * 16 + kcg * 4 + r);
            *(unsigned short*)(smem + plane * 1024 +
                ((rowh * 16 + (jrel & 7) * 2) ^ wswz)) = f2bf(v);
          }
      }
    }
    __syncthreads();
    s16x8 wfv[4];
#pragma unroll
    for (int ks2 = 0; ks2 < 4; ks2++)
      wfv[ks2] = *(const s16x8*)((const char*)W2c +
                   (p * 16 + ks2 * 4 + kcg) * 512 + ko * 16);
#pragma unroll
    for (int ks2 = 0; ks2 < 4; ks2++) {
      const int plane = ks2 * 4 + kcg;
      s16x8 hf = *(const s16x8*)(smem + plane * 1024 +
                                 (h_rdrow ^ ((unsigned)(plane & 3) << 5)));
      acc2 = __builtin_amdgcn_mfma_f32_16x16x32_bf16(hf, wfv[ks2], acc2, 0, 0, 0);
    }
  }

  // ---- epilogue: +b2, store (29 of 32 cols) ----
  if (ko < KOUT) {
    const float bb = b2c[ko];
    const int orow0 = m0 + (w & 3) * 16 + kcg * 4;
#pragma unroll
    for (int r = 0; r < 4; r++)
      out[(size_t)(orow0 + r) * KOUT + ko] = acc2[r] + bb;
  }

#undef STAGE_A
#undef GLS_B
#undef K_STEP
}

// ---------------------------------------------------------------------------
extern "C" void kernel_launch(void* const* d_in, const int* in_sizes, int n_in,
                              void* d_out, int out_size, void* d_ws, size_t ws_size,
                              hipStream_t stream) {
  const float* f   = (const float*)d_in[0];
  const float* g   = (const float*)d_in[1];
  const float* W1t = (const float*)d_in[2];
  const float* b1t = (const float*)d_in[3];
  const float* W1p = (const float*)d_in[4];
  const float* b1p = (const float*)d_in[5];
  const float* W2  = (const float*)d_in[6];
  const float* b2  = (const float*)d_in[7];
  float* out = (float*)d_out;

  unsigned short* Wc  = (unsigned short*)d_ws;
  unsigned short* W2c = Wc + WC_ELEMS;
  float* bcp  = (float*)(W2c + W2C_ELEMS);
  float* b2cp = bcp + 512;

  prep_kernel<<<WC_ELEMS / 512, 512, 0, stream>>>(W1t, b1t, W1p, b1p, W2, b2,
                                                  Wc, W2c, bcp, b2cp);
  joint_kernel<<<N_ROWS / 64, 512, 0, stream>>>(f, g, Wc, W2c, bcp, b2cp, out);
}

// Round 7
// 56.507 us; speedup vs baseline: 1.0602x; 1.0602x over previous
//
#include <hip/hip_runtime.h>

// ---------------------------------------------------------------------------
// Joint network: y = relu(f@W1t^T + g@W1p^T + (b1t+b1p)) @ W2^T + b2
// N=32768, K1=1344 (1024 f + 320 g), J=512, KOUT=29. fp32 in/out, bf16 MFMA.
// R7: ONE 1024-thread block per CU (BM=128, full J). Halves per-CU L2
//     B-traffic vs R6, occupancy 16 waves/CU. B tri-buffered gls issued
//     2 steps ahead (VMCNT(3) ledger); A reg-staged depth-2 (unchanged).
// ---------------------------------------------------------------------------

typedef float  f32x4  __attribute__((ext_vector_type(4)));
typedef short  s16x8  __attribute__((ext_vector_type(8)));   // 8 bf16
typedef short  s16x4  __attribute__((ext_vector_type(4)));   // 4 bf16

#define N_ROWS   32768
#define NKS      42            // K1 / 32
#define KOUT     29

#define WC_ELEMS   (NKS * 4 * 512 * 8)   // 688128 bf16: [ks][kc][j][8]
#define W2C_ELEMS  (64 * 32 * 8)         // 16384 bf16:  [jc][kout32][8]

#define VMCNT(n)   asm volatile("s_waitcnt vmcnt(" #n ")" ::: "memory")
#define LGKM0()    asm volatile("s_waitcnt lgkmcnt(0)" ::: "memory")
#define SBAR()     __builtin_amdgcn_s_barrier()
#define SCHEDB()   __builtin_amdgcn_sched_barrier(0)
#define PRIO(n)    __builtin_amdgcn_s_setprio(n)

typedef const __attribute__((address_space(1))) unsigned int* gp_t;
typedef __attribute__((address_space(3))) unsigned int* lp_t;

static __device__ __forceinline__ void gls16(const void* g, void* l) {
  __builtin_amdgcn_global_load_lds((gp_t)g, (lp_t)l, 16, 0, 0);
}

static __device__ __forceinline__ unsigned short f2bf(float x) {
  union { float f; unsigned u; } v; v.f = x;
  unsigned r = v.u + 0x7fffu + ((v.u >> 16) & 1u);   // RNE
  return (unsigned short)(r >> 16);
}

// ---------------------------------------------------------------------------
__global__ __launch_bounds__(512) void prep_kernel(
    const float* __restrict__ W1t, const float* __restrict__ b1t,
    const float* __restrict__ W1p, const float* __restrict__ b1p,
    const float* __restrict__ W2,  const float* __restrict__ b2,
    unsigned short* __restrict__ Wc, unsigned short* __restrict__ W2c,
    float* __restrict__ bc, float* __restrict__ b2c) {
  int idx = blockIdx.x * 512 + threadIdx.x;
  if (idx < WC_ELEMS) {
    int e  = idx & 7;
    int j  = (idx >> 3) & 511;
    int kc = (idx >> 12) & 3;
    int ks = idx >> 14;
    int c  = ks * 32 + kc * 8 + e;
    float v = (c < 1024) ? W1t[j * 1024 + c] : W1p[j * 320 + (c - 1024)];
    Wc[idx] = f2bf(v);
  }
  if (idx < W2C_ELEMS) {
    int e  = idx & 7;
    int ko = (idx >> 3) & 31;
    int jc = idx >> 8;
    int j  = jc * 8 + e;
    float v = (ko < KOUT) ? W2[ko * 512 + j] : 0.0f;
    W2c[idx] = f2bf(v);
  }
  if (idx < 512) bc[idx]  = b1t[idx] + b1p[idx];
  if (idx < 32)  b2c[idx] = (idx < KOUT) ? b2[idx] : 0.0f;
}

// ---------------------------------------------------------------------------
// 256 blocks x 1024 threads (16 waves, 1 block/CU). Block tile 128 x 512.
// Wave w: wm=w>>3 (0..1), wn=w&7 (0..7): rows wm*64+[0,64), cols wn*64+[0,64).
// LDS: A dbuf [2][4kc][128row][8] @0      (16 KB, XOR-swizzled)
//      B tri  [3][4kc][512j][8]   @16384  (96 KB, gls-linear, 2-step-ahead)
//      phase2 h-chunk [16pl][128r][8] @0  (32 KB, aliases A + B0 low half)
// Total 112 KB -> 1 block/CU, 16 waves/CU.
// ---------------------------------------------------------------------------
__global__ __launch_bounds__(1024, 4) void joint_kernel(
    const float* __restrict__ f, const float* __restrict__ g,
    const unsigned short* __restrict__ Wc, const unsigned short* __restrict__ W2c,
    const float* __restrict__ bc, const float* __restrict__ b2c,
    float* __restrict__ out) {
  __shared__ __align__(16) char smem[114688];

  const int tid = threadIdx.x;
  const int l   = tid & 63;
  const int w   = tid >> 6;          // wave 0..15
  const int wm  = w >> 3;            // 0..1 (rows wm*64)
  const int wn  = w & 7;             // 0..7 (cols wn*64)
  const int m0  = blockIdx.x * 128;

  // A staging: row = tid>>3 (128 rows), kq = tid&7 (8 x f32x4 = 32 k)
  const int srow = tid >> 3;
  const int kq   = tid & 7;
  const char* fA = (const char*)(f + (size_t)(m0 + srow) * 1024 + kq * 4);
  const char* gA = (const char*)(g + (size_t)(m0 + srow) * 320  + kq * 4);
  const int kcpl = kq >> 1;
  const unsigned a_wr = (unsigned)(kcpl * 2048 +
      ((srow * 16 + (kq & 1) * 8) ^ (kcpl << 5)));

  // fragment read offsets
  const int kcg = l >> 4;            // 0..3
  const int lc  = l & 15;
  const unsigned a_rd = (unsigned)(kcg * 2048 + ((lc * 16) ^ (kcg << 5)) +
                                   wm * 1024);
  const unsigned b_rd = (unsigned)(16384 + kcg * 8192 + (wn * 64 + lc) * 16);

  f32x4 acc[4][4];
#pragma unroll
  for (int m = 0; m < 4; m++)
#pragma unroll
    for (int n = 0; n < 4; n++) acc[m][n] = (f32x4)(0.0f);

  f32x4 rawE, rawO;   // A prefetch ping-pong (depth 2)

#define STAGE_A(BUF, SRCREG) {                                              \
    s16x4 hv;                                                               \
    hv[0] = (short)f2bf(SRCREG[0]); hv[1] = (short)f2bf(SRCREG[1]);         \
    hv[2] = (short)f2bf(SRCREG[2]); hv[3] = (short)f2bf(SRCREG[3]);         \
    *(s16x4*)(smem + (BUF) * 8192 + a_wr) = hv;                             \
  }

  // 32 KB B tile, 1024 threads -> 2 x gls16 per thread, linear layout.
#define GLS_B(T, BUF) {                                                     \
    const char* bs_ = (const char*)Wc + (size_t)(T) * 32768 + tid * 16;     \
    char* bd_ = smem + 16384 + (BUF) * 32768 + tid * 16;                    \
    gls16(bs_,          bd_);                                               \
    gls16(bs_ + 16384,  bd_ + 16384);                                       \
  }

  // Step T: gls B(T+2) (2-step-ahead), read A/B frags, issue A(T+2),
  // 16 MFMA, stage A(T+1), VMCNT(3) leaves {glsB(T+2)x2, A(T+2)} in
  // flight across the barrier. B(T+1) (older than A(T+1)) is drained by
  // STAGE_A's compiler wait, so buf (T+1)%3 is valid at the barrier.
#define K_STEP(T, CUR, NXT, CONS, ISSU, DO_B, DO_A, ASRC, DO_WR, VMACRO) {  \
    if (DO_B) { GLS_B((T) + 2, NXT); }                                      \
    s16x8 bq[4];                                                            \
    _Pragma("unroll")                                                       \
    for (int n = 0; n < 4; n++)                                             \
      bq[n] = *(const s16x8*)(smem + (CUR) * 32768 + b_rd + n * 256);       \
    s16x8 af[4];                                                            \
    _Pragma("unroll")                                                       \
    for (int m = 0; m < 4; m++)                                             \
      af[m] = *(const s16x8*)(smem + ((T) & 1) * 8192 + a_rd + m * 256);    \
    if (DO_A) { ISSU = *(const f32x4*)(ASRC); }                             \
    SCHEDB();                                                               \
    PRIO(1);                                                                \
    _Pragma("unroll")                                                       \
    for (int m = 0; m < 4; m++)                                             \
      _Pragma("unroll")                                                     \
      for (int n = 0; n < 4; n++)                                           \
        acc[m][n] = __builtin_amdgcn_mfma_f32_16x16x32_bf16(                \
            af[m], bq[n], acc[m][n], 0, 0, 0);                              \
    PRIO(0);                                                                \
    if (DO_WR) { STAGE_A(((T) + 1) & 1, CONS); }                            \
    VMACRO;                                                                 \
    LGKM0();                                                                \
    SBAR();                                                                 \
  }

  // ---- prologue: gls B(0)->buf0, B(1)->buf1; A(0),A(1); stage A(0) ----
  GLS_B(0, 0);
  GLS_B(1, 1);
  SCHEDB();
  rawE = *(const f32x4*)(fA);          // A(0)
  rawO = *(const f32x4*)(fA + 128);    // A(1)
  STAGE_A(0, rawE);                    // compiler vmcnt(1): drains gls + A(0)
  VMCNT(1);
  LGKM0();
  SBAR();

  // ---- K loop: T=0..41, unroll 6 (B mod 3, A parity 2) ----
  for (int t2 = 0; t2 < 30; t2 += 6) {
    K_STEP(t2 + 0, 0, 2, rawO, rawE, 1, 1, fA + (t2 + 2) * 128, 1, VMCNT(3));
    K_STEP(t2 + 1, 1, 0, rawE, rawO, 1, 1, fA + (t2 + 3) * 128, 1, VMCNT(3));
    K_STEP(t2 + 2, 2, 1, rawO, rawE, 1, 1, fA + (t2 + 4) * 128, 1, VMCNT(3));
    K_STEP(t2 + 3, 0, 2, rawE, rawO, 1, 1, fA + (t2 + 5) * 128, 1, VMCNT(3));
    K_STEP(t2 + 4, 1, 0, rawO, rawE, 1, 1, fA + (t2 + 6) * 128, 1, VMCNT(3));
    K_STEP(t2 + 5, 2, 1, rawE, rawO, 1, 1, fA + (t2 + 7) * 128, 1, VMCNT(3));
  }
  // T=30..39: A(T+2) comes from g (col >= 1024)
  K_STEP(30, 0, 2, rawO, rawE, 1, 1, gA + 0 * 128, 1, VMCNT(3));
  K_STEP(31, 1, 0, rawE, rawO, 1, 1, gA + 1 * 128, 1, VMCNT(3));
  K_STEP(32, 2, 1, rawO, rawE, 1, 1, gA + 2 * 128, 1, VMCNT(3));
  K_STEP(33, 0, 2, rawE, rawO, 1, 1, gA + 3 * 128, 1, VMCNT(3));
  K_STEP(34, 1, 0, rawO, rawE, 1, 1, gA + 4 * 128, 1, VMCNT(3));
  K_STEP(35, 2, 1, rawE, rawO, 1, 1, gA + 5 * 128, 1, VMCNT(3));
  K_STEP(36, 0, 2, rawO, rawE, 1, 1, gA + 6 * 128, 1, VMCNT(3));
  K_STEP(37, 1, 0, rawE, rawO, 1, 1, gA + 7 * 128, 1, VMCNT(3));
  K_STEP(38, 2, 1, rawO, rawE, 1, 1, gA + 8 * 128, 1, VMCNT(3));
  K_STEP(39, 0, 2, rawE, rawO, 1, 1, gA + 9 * 128, 1, VMCNT(3));
  // T=40: no gls/A-issue; stage A(41) from rawO. T=41: compute only.
  K_STEP(40, 1, 0, rawO, rawE, 0, 0, fA, 1, VMCNT(0));
  K_STEP(41, 2, 1, rawE, rawO, 0, 0, fA, 0, VMCNT(0));

  // ---- phase 2: y = relu(h+bias) @ W2^T + b2, h streamed in 4 chunks ----
  // Chunk p: j in [p*128,(p+1)*128), written by the 4 waves with wn>>1==p.
  // Then all 16 waves MFMA: wave w owns y rows (w&7)*16.., ko (w>>3)*16..
  float bias[4];
#pragma unroll
  for (int n = 0; n < 4; n++) bias[n] = bc[wn * 64 + n * 16 + lc];

  f32x4 acc2 = (f32x4)(0.0f);
  const int myp = wn >> 1;
  const int ko  = (w >> 3) * 16 + lc;
  const unsigned h_rdrow = (unsigned)(((w & 7) * 16 + lc) * 16);

#pragma unroll
  for (int p = 0; p < 4; p++) {
    __syncthreads();                 // h chunk region free
    if (myp == p) {
#pragma unroll
      for (int n = 0; n < 4; n++) {
        const int jrel  = (wn & 1) * 64 + n * 16 + lc;
        const int plane = jrel >> 3;
        const unsigned wswz = (unsigned)((plane & 3) << 5);
#pragma unroll
        for (int m = 0; m < 4; m++)
#pragma unroll
          for (int r = 0; r < 4; r++) {
            float v = fmaxf(acc[m][n][r] + bias[n], 0.0f);
            const unsigned rowh = (unsigned)(wm * 64 + m * 16 + kcg * 4 + r);
            *(unsigned short*)(smem + plane * 2048 +
                ((rowh * 16 + (jrel & 7) * 2) ^ wswz)) = f2bf(v);
          }
      }
    }
    __syncthreads();
    s16x8 wfv[4];
#pragma unroll
    for (int ks2 = 0; ks2 < 4; ks2++)
      wfv[ks2] = *(const s16x8*)((const char*)W2c +
                   (p * 16 + ks2 * 4 + kcg) * 512 + ko * 16);
#pragma unroll
    for (int ks2 = 0; ks2 < 4; ks2++) {
      const int plane = ks2 * 4 + kcg;
      s16x8 hf = *(const s16x8*)(smem + plane * 2048 +
                                 (h_rdrow ^ ((unsigned)(plane & 3) << 5)));
      acc2 = __builtin_amdgcn_mfma_f32_16x16x32_bf16(hf, wfv[ks2], acc2, 0, 0, 0);
    }
  }

  // ---- epilogue: +b2, store (29 of 32 cols) ----
  if (ko < KOUT) {
    const float bb = b2c[ko];
    const int orow0 = m0 + (w & 7) * 16 + kcg * 4;
#pragma unroll
    for (int r = 0; r < 4; r++)
      out[(size_t)(orow0 + r) * KOUT + ko] = acc2[r] + bb;
  }

#undef STAGE_A
#undef GLS_B
#undef K_STEP
}

// ---------------------------------------------------------------------------
extern "C" void kernel_launch(void* const* d_in, const int* in_sizes, int n_in,
                              void* d_out, int out_size, void* d_ws, size_t ws_size,
                              hipStream_t stream) {
  const float* f   = (const float*)d_in[0];
  const float* g   = (const float*)d_in[1];
  const float* W1t = (const float*)d_in[2];
  const float* b1t = (const float*)d_in[3];
  const float* W1p = (const float*)d_in[4];
  const float* b1p = (const float*)d_in[5];
  const float* W2  = (const float*)d_in[6];
  const float* b2  = (const float*)d_in[7];
  float* out = (float*)d_out;

  unsigned short* Wc  = (unsigned short*)d_ws;
  unsigned short* W2c = Wc + WC_ELEMS;
  float* bcp  = (float*)(W2c + W2C_ELEMS);
  float* b2cp = bcp + 512;

  prep_kernel<<<WC_ELEMS / 512, 512, 0, stream>>>(W1t, b1t, W1p, b1p, W2, b2,
                                                  Wc, W2c, bcp, b2cp);
  joint_kernel<<<N_ROWS / 128, 1024, 0, stream>>>(f, g, Wc, W2c, bcp, b2cp, out);
}